// Round 10
// baseline (930.237 us; speedup 1.0000x reference)
//
#include <hip/hip_runtime.h>
#include <hip/hip_cooperative_groups.h>

namespace cg = cooperative_groups;

#define EMB 128
#define NBUC 1024          // coarse buckets: dst >> 7 (128 nodes per bucket)
#define PWB 128            // weight-prep blocks (128 x 256 = 32768 = both W)

typedef __attribute__((ext_vector_type(8))) short short8;   // 8 bf16 (4 VGPRs)
typedef __attribute__((ext_vector_type(4))) float f32x4;    // MFMA acc

// ---------------- bf16 helpers ----------------
__device__ __forceinline__ unsigned short f2bf(float f) {
    union { float f; unsigned int i; } v; v.f = f;
    unsigned int x = v.i;
    x += 0x7fffu + ((x >> 16) & 1u);   // round-to-nearest-even
    return (unsigned short)(x >> 16);
}
// a += d * unpack_bf16x4(v)
__device__ __forceinline__ void acc_fma4(uint2 v, float d,
                                         float& a0, float& a1, float& a2, float& a3) {
    union { unsigned int i; float f; } t;
    t.i = v.x << 16;          a0 = fmaf(d, t.f, a0);
    t.i = v.x & 0xffff0000u;  a1 = fmaf(d, t.f, a1);
    t.i = v.y << 16;          a2 = fmaf(d, t.f, a2);
    t.i = v.y & 0xffff0000u;  a3 = fmaf(d, t.f, a3);
}
// a += unpack_bf16x4(v)
__device__ __forceinline__ void acc_bf4(uint2 v,
                                        float& a0, float& a1, float& a2, float& a3) {
    union { unsigned int i; float f; } t;
    t.i = v.x << 16;          a0 += t.f;
    t.i = v.x & 0xffff0000u;  a1 += t.f;
    t.i = v.y << 16;          a2 += t.f;
    t.i = v.y & 0xffff0000u;  a3 += t.f;
}

// =====================================================================
// ONE cooperative kernel for the entire 2-layer GCN.  256-thread blocks,
// __launch_bounds__(256, 6): ~84-VGPR budget (phase peak is ~52 -> NO SPILL;
// round 9's (512,8)=64-reg budget spilled and 3x'd the runtime), 6 blocks/CU.
// Phases (grid.sync() between):
//   A0: zero bucket totals
//   A : edge histogram (blocks >= PWB) || W1/W2 pre-swizzle (blocks < PWB)
//   B : block 0 scans bucket totals -> base[], gcnt[]
//   C : reservation scatter (blocks < nb/2) || layer-1 GEMM (blocks >= nb/2)
//   D : bucket -> CSR (R, adj, dis)
//   E : fused gather1(dis-fold)+relu+bias + layer-2 GEMM (dis-scaled out)
//   F : gather2 (plain adds) + bias -> f32 out
// Gathers: proven 32 thr/node + uint2 (random-granule-HBM-bound; shape
// changes only lose).  LDS arena 17408 B = gemm1 epilogue 64x136 bf16.
// =====================================================================
__global__ __launch_bounds__(256, 6) void k_all(
    const int* __restrict__ src, const int* __restrict__ dst, int E,
    const float* __restrict__ emb,
    const float* __restrict__ W1, const float* __restrict__ b1,
    const float* __restrict__ W2, const float* __restrict__ b2,
    float* __restrict__ out, int N,
    int* __restrict__ tot, int* __restrict__ base, int* __restrict__ gcnt,
    int* __restrict__ R, int* __restrict__ adj, float* __restrict__ dis,
    unsigned short* __restrict__ W1s, unsigned short* __restrict__ W2s,
    int* __restrict__ part,
    unsigned short* __restrict__ Y1, unsigned short* __restrict__ Y2)
{
    cg::grid_group g = cg::this_grid();
    __shared__ __align__(16) char smem[17408];
    const int tid = threadIdx.x;
    const int bid = blockIdx.x;
    const int nb  = gridDim.x;
    const int wave = tid >> 6;                 // 0..3
    const int lane = tid & 63;
    const int q = lane >> 4, nn = lane & 15;

    // ---------------- A0: zero bucket totals ----------------
    {
        int i = bid * 256 + tid;
        if (i < NBUC) tot[i] = 0;
    }
    g.sync();

    // ---------------- A: weight pre-swizzle || edge histogram ----------------
    if (bid < PWB) {
        // Wb[kk][ct][q][nn][j] = W[kk*32+q*8+j][ct*16+nn]
        int gid = bid * 256 + tid;                 // 0..32767
        const float* W = (gid < 16384) ? W1 : W2;
        unsigned short* Ws = (gid < 16384) ? W1s : W2s;
        int idx = gid & 16383;
        int k = idx >> 7, n = idx & 127;
        int kk = k >> 5, qq = (k >> 3) & 3, j = k & 7;
        int ct = n >> 4, n2 = n & 15;
        Ws[((((kk * 8 + ct) * 4 + qq) * 16 + n2) << 3) + j] = f2bf(W[idx]);
    } else {
        int* h = (int*)smem;
        for (int i = tid; i < NBUC; i += 256) h[i] = 0;
        __syncthreads();
        int nhb = nb - PWB;
        int chunk = (E + nhb - 1) / nhb;
        int s = (bid - PWB) * chunk, e = min(E, s + chunk);
        for (int i = s + tid; i < e; i += 256)
            atomicAdd(&h[dst[i] >> 7], 1);
        __syncthreads();
        for (int i = tid; i < NBUC; i += 256) {
            int v = h[i];
            if (v) atomicAdd(&tot[i], v);
        }
    }
    g.sync();

    // ---------------- B: scan bucket totals (block 0, 4 buckets/thread) --------
    if (bid == 0) {
        int* a = (int*)smem;
        int v0 = tot[4 * tid], v1 = tot[4 * tid + 1];
        int v2 = tot[4 * tid + 2], v3 = tot[4 * tid + 3];
        int sp = v0 + v1 + v2 + v3;
        a[tid] = sp;
        __syncthreads();
        for (int off = 1; off < 256; off <<= 1) {
            int v = (tid >= off) ? a[tid - off] : 0;
            __syncthreads();
            a[tid] += v;
            __syncthreads();
        }
        int ex = a[tid] - sp;                      // exclusive over 4-groups
        base[4 * tid] = ex;               gcnt[4 * tid] = ex;
        base[4 * tid + 1] = ex + v0;      gcnt[4 * tid + 1] = ex + v0;
        base[4 * tid + 2] = ex + v0 + v1; gcnt[4 * tid + 2] = ex + v0 + v1;
        base[4 * tid + 3] = ex + v0 + v1 + v2;
        gcnt[4 * tid + 3] = ex + v0 + v1 + v2;
        if (tid == 255) base[NBUC] = E;
    }
    g.sync();

    // ---------------- C: reservation scatter || layer-1 GEMM ----------------
    const int SCB = nb >> 1;
    if (bid < SCB) {
        int* cnt = (int*)smem;
        for (int i = tid; i < NBUC; i += 256) cnt[i] = 0;
        __syncthreads();
        int chunk = (E + SCB - 1) / SCB;
        int s = bid * chunk, e = min(E, s + chunk);
        for (int i = s + tid; i < e; i += 256)
            atomicAdd(&cnt[dst[i] >> 7], 1);
        __syncthreads();
        for (int i = tid; i < NBUC; i += 256) {
            int c = cnt[i];
            cnt[i] = c ? atomicAdd(&gcnt[i], c) : 0;   // LDS cursor := global base
        }
        __syncthreads();
        for (int i = s + tid; i < e; i += 256) {
            int d = dst[i];
            int pos = atomicAdd(&cnt[d >> 7], 1);
            part[pos] = src[i] | ((d & 127) << 17);    // src < 2^17, local in [0,128)
        }
    } else {
        // gemm1: 64-row tiles, 4 waves x 16 rows; B-frags straight from the
        // 32KB L1/L2-resident W1s table.  Y1 unscaled bf16.
        int ntile = (N + 63) >> 6;
        unsigned short* lds = (unsigned short*)smem;   // 64 x 136 epilogue stage
        for (int tile = bid - SCB; tile < ntile; tile += nb - SCB) {
            int row0 = (tile << 6) + wave * 16;
            int arow = row0 + nn;
            int arc = arow < N ? arow : N - 1;
            f32x4 acc[8];
#pragma unroll
            for (int ct = 0; ct < 8; ++ct) acc[ct] = (f32x4){0.f, 0.f, 0.f, 0.f};
#pragma unroll
            for (int kk = 0; kk < 4; ++kk) {
                const float* xp = emb + (size_t)arc * EMB + kk * 32 + q * 8;
                float4 u0 = *(const float4*)xp;
                float4 u1 = *(const float4*)(xp + 4);
                short8 af;
                af[0] = (short)f2bf(u0.x); af[1] = (short)f2bf(u0.y);
                af[2] = (short)f2bf(u0.z); af[3] = (short)f2bf(u0.w);
                af[4] = (short)f2bf(u1.x); af[5] = (short)f2bf(u1.y);
                af[6] = (short)f2bf(u1.z); af[7] = (short)f2bf(u1.w);
#pragma unroll
                for (int ct = 0; ct < 8; ++ct) {
                    short8 bf = *(const short8*)(W1s +
                        ((((kk * 8 + ct) * 4 + q) * 16 + nn) << 3));
                    acc[ct] = __builtin_amdgcn_mfma_f32_16x16x32_bf16(af, bf, acc[ct], 0, 0, 0);
                }
            }
            __syncthreads();
#pragma unroll
            for (int ct = 0; ct < 8; ++ct)
#pragma unroll
                for (int r = 0; r < 4; ++r)
                    lds[(wave * 16 + q * 4 + r) * 136 + ct * 16 + nn] =
                        f2bf(acc[ct][r]);
            __syncthreads();
            int rbase = tile << 6;
            for (int i = tid; i < 1024; i += 256) {
                int row = i >> 4, off = i & 15;
                int grow = rbase + row;
                if (grow < N)
                    *((uint4*)(Y1 + (size_t)grow * EMB) + off) =
                        *(const uint4*)(lds + row * 136 + off * 8);
            }
            __syncthreads();
        }
    }
    g.sync();

    // ---------------- D: bucket -> CSR ----------------
    {
        int nbuck = (N + 127) >> 7;
        int* hist = (int*)smem;
        int* sc   = hist + 128;
        int* cnt  = sc + 128;
        for (int b = bid; b < nbuck; b += nb) {
            int n0 = b << 7;
            int nn2 = min(128, N - n0);
            int s = base[b], e = base[b + 1];
            if (tid < 128) hist[tid] = 0;
            __syncthreads();
            for (int i = s + tid; i < e; i += 256)
                atomicAdd(&hist[part[i] >> 17], 1);
            __syncthreads();
            if (tid < 128) sc[tid] = hist[tid];
            __syncthreads();
            for (int off = 1; off < 128; off <<= 1) {
                int v = 0;
                if (tid < 128 && tid >= off) v = sc[tid - off];
                __syncthreads();
                if (tid < 128) sc[tid] += v;
                __syncthreads();
            }
            if (tid < 128) {
                int ex = sc[tid] - hist[tid];
                cnt[tid] = ex;
                if (tid < nn2) {
                    R[n0 + tid] = s + ex;
                    dis[n0 + tid] = rsqrtf((float)hist[tid] + 1.0f);   // +1 self-loop
                }
            }
            if (b == 0 && tid == 0) R[N] = E;
            __syncthreads();
            for (int i = s + tid; i < e; i += 256) {
                int p = part[i];
                int pos = atomicAdd(&cnt[p >> 17], 1);
                adj[s + pos] = p & 0x1FFFF;
            }
            __syncthreads();   // cnt reused next bucket
        }
    }
    g.sync();

    // ------- E: fused gather1 (dis-fold) + relu + layer-2 GEMM (dis-scaled) -------
    {
        int ntile = (N + 15) >> 4;                 // 16 nodes per tile
        unsigned short* Hs = (unsigned short*)smem; // [16][136] bf16
        const int nl = tid >> 5;                   // 0..7
        const int lj = (tid & 31) * 4;             // 4 dims per thread
        for (int tile = bid; tile < ntile; tile += nb) {
            // gather 16 nodes in two 8-node halves (32 thr/node each)
#pragma unroll
            for (int half = 0; half < 2; ++half) {
                int n = (tile << 4) + half * 8 + nl;
                float a0 = 0.f, a1 = 0.f, a2 = 0.f, a3 = 0.f;
                if (n < N) {
                    float dv = dis[n];
                    uint2 sv = *(const uint2*)(Y1 + (size_t)n * EMB + lj);
                    acc_fma4(sv, dv, a0, a1, a2, a3);          // self term
                    int e = R[n];
                    const int re = R[n + 1];
                    for (; e + 3 < re; e += 4) {
                        int s0 = adj[e], s1 = adj[e + 1];
                        int s2 = adj[e + 2], s3 = adj[e + 3];
                        float d0 = dis[s0], d1 = dis[s1], d2 = dis[s2], d3 = dis[s3];
                        uint2 v0 = *(const uint2*)(Y1 + (size_t)s0 * EMB + lj);
                        uint2 v1 = *(const uint2*)(Y1 + (size_t)s1 * EMB + lj);
                        uint2 v2 = *(const uint2*)(Y1 + (size_t)s2 * EMB + lj);
                        uint2 v3 = *(const uint2*)(Y1 + (size_t)s3 * EMB + lj);
                        acc_fma4(v0, d0, a0, a1, a2, a3);
                        acc_fma4(v1, d1, a0, a1, a2, a3);
                        acc_fma4(v2, d2, a0, a1, a2, a3);
                        acc_fma4(v3, d3, a0, a1, a2, a3);
                    }
                    for (; e < re; ++e) {
                        int s0 = adj[e];
                        uint2 v0 = *(const uint2*)(Y1 + (size_t)s0 * EMB + lj);
                        acc_fma4(v0, dis[s0], a0, a1, a2, a3);
                    }
                    float4 bb = *(const float4*)(b1 + lj);
                    a0 = fmaxf(dv * a0 + bb.x, 0.f);
                    a1 = fmaxf(dv * a1 + bb.y, 0.f);
                    a2 = fmaxf(dv * a2 + bb.z, 0.f);
                    a3 = fmaxf(dv * a3 + bb.w, 0.f);
                }
                uint2 pk;
                pk.x = (unsigned)f2bf(a0) | ((unsigned)f2bf(a1) << 16);
                pk.y = (unsigned)f2bf(a2) | ((unsigned)f2bf(a3) << 16);
                *(uint2*)(Hs + (half * 8 + nl) * 136 + lj) = pk;  // zeros for n>=N
            }
            __syncthreads();

            // MFMA: 16x128 H @ 128x128 W2; wave covers ct0=2w, ct1=2w+1
            const int ct0 = wave * 2, ct1 = wave * 2 + 1;
            f32x4 acc0 = (f32x4){0.f, 0.f, 0.f, 0.f};
            f32x4 acc1 = (f32x4){0.f, 0.f, 0.f, 0.f};
#pragma unroll
            for (int kk = 0; kk < 4; ++kk) {
                short8 af = *(const short8*)(Hs + nn * 136 + kk * 32 + q * 8);
                short8 bf0 = *(const short8*)(W2s +
                    ((((kk * 8 + ct0) * 4 + q) * 16 + nn) << 3));
                short8 bf1 = *(const short8*)(W2s +
                    ((((kk * 8 + ct1) * 4 + q) * 16 + nn) << 3));
                acc0 = __builtin_amdgcn_mfma_f32_16x16x32_bf16(af, bf0, acc0, 0, 0, 0);
                acc1 = __builtin_amdgcn_mfma_f32_16x16x32_bf16(af, bf1, acc1, 0, 0, 0);
            }
            __syncthreads();   // all A-frag reads done before D overwrites Hs

            // D map: row m=q*4+r, col ct*16+nn; scale rows by dis[row]
#pragma unroll
            for (int r = 0; r < 4; ++r) {
                int m = q * 4 + r;
                int gm = (tile << 4) + m;
                float dm = dis[gm < N ? gm : N - 1];
                Hs[m * 136 + ct0 * 16 + nn] = f2bf(acc0[r] * dm);
                Hs[m * 136 + ct1 * 16 + nn] = f2bf(acc1[r] * dm);
            }
            __syncthreads();

            // coalesced store: 16 rows x 256B, 16B per thread
            {
                int row = tid >> 4, off = tid & 15;
                int gr = (tile << 4) + row;
                if (gr < N)
                    *((uint4*)(Y2 + (size_t)gr * EMB) + off) =
                        *(const uint4*)(Hs + row * 136 + off * 8);
            }
            __syncthreads();   // store reads done before next tile's pack
        }
    }
    g.sync();

    // ---------------- F: gather2 (plain adds; Y2 pre-scaled) ----------------
    {
        int nch = (N + 7) >> 3;                    // 8 nodes per block-chunk
        const int nl = tid >> 5;
        const int lj = (tid & 31) * 4;
        for (int ch = bid; ch < nch; ch += nb) {
            int n = (ch << 3) + nl;
            if (n >= N) continue;
            float a0 = 0.f, a1 = 0.f, a2 = 0.f, a3 = 0.f;
            uint2 sv = *(const uint2*)(Y2 + (size_t)n * EMB + lj);
            acc_bf4(sv, a0, a1, a2, a3);
            int e = R[n];
            const int re = R[n + 1];
            for (; e + 3 < re; e += 4) {
                int s0 = adj[e], s1 = adj[e + 1], s2 = adj[e + 2], s3 = adj[e + 3];
                uint2 v0 = *(const uint2*)(Y2 + (size_t)s0 * EMB + lj);
                uint2 v1 = *(const uint2*)(Y2 + (size_t)s1 * EMB + lj);
                uint2 v2 = *(const uint2*)(Y2 + (size_t)s2 * EMB + lj);
                uint2 v3 = *(const uint2*)(Y2 + (size_t)s3 * EMB + lj);
                acc_bf4(v0, a0, a1, a2, a3); acc_bf4(v1, a0, a1, a2, a3);
                acc_bf4(v2, a0, a1, a2, a3); acc_bf4(v3, a0, a1, a2, a3);
            }
            for (; e < re; ++e) {
                uint2 v0 = *(const uint2*)(Y2 + (size_t)adj[e] * EMB + lj);
                acc_bf4(v0, a0, a1, a2, a3);
            }
            float dv = dis[n];
            float4 bb = *(const float4*)(b2 + lj);
            float4 o = { dv * a0 + bb.x, dv * a1 + bb.y,
                         dv * a2 + bb.z, dv * a3 + bb.w };
            *(float4*)(out + (size_t)n * EMB + lj) = o;
        }
    }
}

extern "C" void kernel_launch(void* const* d_in, const int* in_sizes, int n_in,
                              void* d_out, int out_size, void* d_ws, size_t ws_size,
                              hipStream_t stream) {
    const int* ei = (const int*)d_in[0];
    int E = in_sizes[0] / 2;
    const float* emb = (const float*)d_in[2];
    int N = in_sizes[2] / EMB;
    const float* W1 = (const float*)d_in[3];
    const float* b1 = (const float*)d_in[4];
    const float* W2 = (const float*)d_in[5];
    const float* b2 = (const float*)d_in[6];
    float* out = (float*)d_out;

    const int* src = ei;
    const int* dstp = ei + E;

    // ws: dis | R | base | tot | gcnt | adj | W1s | W2s | Y2 (part overlays Y2;
    // dead before phase E writes Y2).  Y1 lives in d_out bytes (dead before
    // phase F writes d_out f32).
    char* w = (char*)d_ws;
    auto take = [&](size_t bytes) { char* p = w; w += (bytes + 511) & ~(size_t)511; return p; };
    float* dis  = (float*)take((size_t)N * 4);
    int*   R    = (int*)  take((size_t)(N + 1) * 4);
    int*   base = (int*)  take((size_t)(NBUC + 1) * 4);
    int*   tot  = (int*)  take((size_t)NBUC * 4);
    int*   gcnt = (int*)  take((size_t)NBUC * 4);
    int*   adj  = (int*)  take((size_t)E * 4);
    unsigned short* W1s = (unsigned short*)take((size_t)EMB * EMB * 2);
    unsigned short* W2s = (unsigned short*)take((size_t)EMB * EMB * 2);
    unsigned short* Y2  = (unsigned short*)take((size_t)N * EMB * 2);
    int*   part = (int*)Y2;                                  // overlay (dead before Y2)
    unsigned short* Y1 = (unsigned short*)d_out;             // overlay in d_out

    // Grid sized to guaranteed co-residency (cooperative requirement).
    static int maxb = -1;
    if (maxb < 0) {
        hipOccupancyMaxActiveBlocksPerMultiprocessor(&maxb, (const void*)k_all, 256, 0);
        if (maxb < 1) maxb = 1;
    }
    int nb = maxb * 256;
    if (nb > 2048) nb = 2048;
    if (nb < 256) nb = 256;

    void* args[] = {
        (void*)&src, (void*)&dstp, (void*)&E, (void*)&emb,
        (void*)&W1, (void*)&b1, (void*)&W2, (void*)&b2,
        (void*)&out, (void*)&N,
        (void*)&tot, (void*)&base, (void*)&gcnt,
        (void*)&R, (void*)&adj, (void*)&dis,
        (void*)&W1s, (void*)&W2s, (void*)&part,
        (void*)&Y1, (void*)&Y2
    };
    hipLaunchCooperativeKernel((void*)k_all, dim3(nb), dim3(256), args, 0, stream);
}

// Round 11
// 319.674 us; speedup vs baseline: 2.9100x; 2.9100x over previous
//
#include <hip/hip_runtime.h>

#define EMB 128
#define NBUC 1024          // coarse buckets: dst >> 7 (128 nodes per bucket)
#define NPART 256          // partition blocks for hist/scatter
#define PREPB 128          // prep_w blocks appended to k_start

typedef __attribute__((ext_vector_type(8))) short short8;   // 8 bf16 (4 VGPRs)
typedef __attribute__((ext_vector_type(4))) float f32x4;    // MFMA acc

// ---------------- bf16 helpers ----------------
__device__ __forceinline__ unsigned short f2bf(float f) {
    union { float f; unsigned int i; } v; v.f = f;
    unsigned int x = v.i;
    x += 0x7fffu + ((x >> 16) & 1u);   // round-to-nearest-even
    return (unsigned short)(x >> 16);
}
// a[0..7] += d * unpack_bf16x8(v)
__device__ __forceinline__ void acc_fma8(uint4 v, float d, float* a) {
    union { unsigned int i; float f; } t;
    t.i = v.x << 16;          a[0] = fmaf(d, t.f, a[0]);
    t.i = v.x & 0xffff0000u;  a[1] = fmaf(d, t.f, a[1]);
    t.i = v.y << 16;          a[2] = fmaf(d, t.f, a[2]);
    t.i = v.y & 0xffff0000u;  a[3] = fmaf(d, t.f, a[3]);
    t.i = v.z << 16;          a[4] = fmaf(d, t.f, a[4]);
    t.i = v.z & 0xffff0000u;  a[5] = fmaf(d, t.f, a[5]);
    t.i = v.w << 16;          a[6] = fmaf(d, t.f, a[6]);
    t.i = v.w & 0xffff0000u;  a[7] = fmaf(d, t.f, a[7]);
}
// a += unpack_bf16x4(v)
__device__ __forceinline__ void acc_bf4(uint2 v,
                                        float& a0, float& a1, float& a2, float& a3) {
    union { unsigned int i; float f; } t;
    t.i = v.x << 16;          a0 += t.f;
    t.i = v.x & 0xffff0000u;  a1 += t.f;
    t.i = v.y << 16;          a2 += t.f;
    t.i = v.y & 0xffff0000u;  a3 += t.f;
}

// ============ CSR build: reservation counting sort ============

__device__ __forceinline__ void p1_body(int bid, int* h, const int* __restrict__ dst,
                                        int* __restrict__ tot, int E, int chunk) {
    for (int i = threadIdx.x; i < NBUC; i += 256) h[i] = 0;
    __syncthreads();
    int s = bid * chunk;
    int e = min(E, s + chunk);
    for (int i = s + threadIdx.x; i < e; i += 256)
        atomicAdd(&h[dst[i] >> 7], 1);
    __syncthreads();
    for (int i = threadIdx.x; i < NBUC; i += 256) {
        int v = h[i];
        if (v) atomicAdd(&tot[i], v);
    }
}

// W pre-swizzle: f32 [128][128] -> bf16 fragment order.
// Wb[kk][ct][q][nn][j] = W[kk*32+q*8+j][ct*16+nn]; lane (q*16+nn) reads its B-frag
// for (kk,ct) as one contiguous 16B short8 at index (kk*8+ct)*64 + lane.
__device__ __forceinline__ void prepw_body(int bid, const float* __restrict__ W1,
                                           const float* __restrict__ W2,
                                           unsigned short* __restrict__ W1s,
                                           unsigned short* __restrict__ W2s) {
    int gid = bid * 256 + threadIdx.x;            // 128 blocks x 256 = 32768
    const float* W = (gid < 16384) ? W1 : W2;
    unsigned short* Ws = (gid < 16384) ? W1s : W2s;
    int idx = gid & 16383;
    int k = idx >> 7, n = idx & 127;
    int kk = k >> 5, q = (k >> 3) & 3, j = k & 7;
    int ct = n >> 4, nn = n & 15;
    int didx = ((((kk * 8 + ct) * 4 + q) * 16 + nn) << 3) + j;
    Ws[didx] = f2bf(W[idx]);
}

// K1: blocks [0,NPART) = hist; [NPART, NPART+PREPB) = weight pre-swizzle.
__global__ __launch_bounds__(256) void k_start(const int* __restrict__ dst,
                                               int* __restrict__ tot, int E, int chunk,
                                               const float* __restrict__ W1,
                                               const float* __restrict__ W2,
                                               unsigned short* __restrict__ W1s,
                                               unsigned short* __restrict__ W2s) {
    __shared__ int h[NBUC];
    int b = blockIdx.x;
    if (b < NPART) p1_body(b, h, dst, tot, E, chunk);
    else           prepw_body(b - NPART, W1, W2, W1s, W2s);
}

// Exclusive scan of bucket totals -> base[]; init global cursors gcnt[].
__global__ __launch_bounds__(1024) void p_scan(const int* __restrict__ tot,
                                               int* __restrict__ base,
                                               int* __restrict__ gcnt, int E) {
    __shared__ int a[NBUC];
    int t = threadIdx.x;
    int v0 = tot[t];
    a[t] = v0;
    __syncthreads();
    for (int off = 1; off < NBUC; off <<= 1) {
        int v = (t >= off) ? a[t - off] : 0;
        __syncthreads();
        a[t] += v;
        __syncthreads();
    }
    int excl = a[t] - v0;
    base[t] = excl;
    gcnt[t] = excl;
    if (t == NBUC - 1) base[NBUC] = E;
}

// Reservation scatter (intra-bucket order arbitrary; p3 re-sorts by node).
__device__ __forceinline__ void scatter_body(int bid, int* cnt,
                                             const int* __restrict__ src,
                                             const int* __restrict__ dst,
                                             int* __restrict__ gcnt,
                                             int* __restrict__ part,
                                             int E, int chunk) {
    for (int i = threadIdx.x; i < NBUC; i += 256) cnt[i] = 0;
    __syncthreads();
    int s = bid * chunk;
    int e = min(E, s + chunk);
    for (int i = s + threadIdx.x; i < e; i += 256)
        atomicAdd(&cnt[dst[i] >> 7], 1);
    __syncthreads();
    for (int i = threadIdx.x; i < NBUC; i += 256) {
        int c = cnt[i];
        cnt[i] = c ? atomicAdd(&gcnt[i], c) : 0;   // LDS cursor := global base
    }
    __syncthreads();
    for (int i = s + threadIdx.x; i < e; i += 256) {
        int d = dst[i];
        int pos = atomicAdd(&cnt[d >> 7], 1);
        part[pos] = src[i] | ((d & 127) << 17);    // src < 2^17, local node in [0,128)
    }
}

__global__ __launch_bounds__(256) void p3_csr(const int* __restrict__ part,
                                              const int* __restrict__ base,
                                              int* __restrict__ R, int* __restrict__ adj,
                                              float* __restrict__ dis, int N, int E) {
    __shared__ int hist[128];
    __shared__ int sc[128];
    __shared__ int cnt[128];
    int b = blockIdx.x;
    int n0 = b * 128;
    int nn = min(128, N - n0);
    int s = base[b], e = base[b + 1];
    int t = threadIdx.x;

    if (t < 128) hist[t] = 0;
    __syncthreads();
    for (int i = s + t; i < e; i += 256)
        atomicAdd(&hist[part[i] >> 17], 1);
    __syncthreads();

    if (t < 128) sc[t] = hist[t];
    __syncthreads();
    for (int off = 1; off < 128; off <<= 1) {
        int v = 0;
        if (t < 128 && t >= off) v = sc[t - off];
        __syncthreads();
        if (t < 128) sc[t] += v;
        __syncthreads();
    }
    if (t < 128) {
        int excl = sc[t] - hist[t];
        cnt[t] = excl;
        if (t < nn) {
            R[n0 + t] = s + excl;
            dis[n0 + t] = rsqrtf((float)hist[t] + 1.0f);   // +1 self-loop
        }
    }
    if (b == 0 && t == 0) R[N] = E;
    __syncthreads();

    for (int i = s + t; i < e; i += 256) {
        int p = part[i];
        int pos = atomicAdd(&cnt[p >> 17], 1);
        adj[s + pos] = p & 0x1FFFF;
    }
}

// ---------------- MFMA GEMM body: Y[n] = bf16(X[n] @ W), UNSCALED ----------------
// 64 nodes/block, 16/wave; K=128 as 4 steps of mfma_f32_16x16x32_bf16.
// Fragment maps (doc-verified): A: m=lane&15, k=q*8+j; B: n=lane&15, k=q*8+j;
// D: n=lane&15, m=q*4+reg.  Used for layer 1 only (dis folded into gather1).
__device__ __forceinline__ void gemm_body(int bid, unsigned short* lds,
    const float* __restrict__ Xv, const unsigned short* __restrict__ Wsw,
    unsigned short* __restrict__ Y, int N)
{
    {
        const uint4* srcp = (const uint4*)Wsw;
        uint4* dstp = (uint4*)lds;
        for (int i = threadIdx.x; i < 2048; i += 256) dstp[i] = srcp[i];
    }
    __syncthreads();

    const int wave = threadIdx.x >> 6;
    const int lane = threadIdx.x & 63;
    const int q = lane >> 4, nn = lane & 15;
    const int row0 = bid * 64 + wave * 16;
    const int arow = row0 + nn;
    const int arc = arow < N ? arow : N - 1;

    f32x4 acc[8];
#pragma unroll
    for (int ct = 0; ct < 8; ++ct) acc[ct] = (f32x4){0.f, 0.f, 0.f, 0.f};

#pragma unroll
    for (int kk = 0; kk < 4; ++kk) {
        const float* xp = Xv + (size_t)arc * EMB + kk * 32 + q * 8;
        float4 u0 = *(const float4*)xp;
        float4 u1 = *(const float4*)(xp + 4);
        short8 af;
        af[0] = (short)f2bf(u0.x); af[1] = (short)f2bf(u0.y);
        af[2] = (short)f2bf(u0.z); af[3] = (short)f2bf(u0.w);
        af[4] = (short)f2bf(u1.x); af[5] = (short)f2bf(u1.y);
        af[6] = (short)f2bf(u1.z); af[7] = (short)f2bf(u1.w);
#pragma unroll
        for (int ct = 0; ct < 8; ++ct) {
            short8 bf = ((const short8*)lds)[(kk * 8 + ct) * 64 + lane];
            acc[ct] = __builtin_amdgcn_mfma_f32_16x16x32_bf16(af, bf, acc[ct], 0, 0, 0);
        }
    }

    __syncthreads();

#pragma unroll
    for (int ct = 0; ct < 8; ++ct) {
#pragma unroll
        for (int r = 0; r < 4; ++r) {
            int ml = wave * 16 + q * 4 + r;
            lds[ml * 136 + ct * 16 + nn] = f2bf(acc[ct][r]);
        }
    }
    __syncthreads();

    const int rbase = bid * 64;
    for (int i = threadIdx.x; i < 1024; i += 256) {
        int row = i >> 4, off = i & 15;
        int grow = rbase + row;
        if (grow < N) {
            uint4 v = *(const uint4*)(lds + row * 136 + off * 8);
            *((uint4*)(Y + (size_t)grow * EMB) + off) = v;
        }
    }
}

// K3: blocks [0,NPART) = reservation scatter; [NPART, NPART+gM) = layer-1 GEMM.
__global__ __launch_bounds__(256) void k_mid(
    const int* __restrict__ src, const int* __restrict__ dstp,
    int* __restrict__ gcnt, int* __restrict__ part, int E, int chunk,
    const float* __restrict__ Xv, const unsigned short* __restrict__ W1s,
    unsigned short* __restrict__ Y, int N)
{
    __shared__ __align__(16) unsigned short smem[16384];   // 32 KB (scatter uses 4 KB)
    int b = blockIdx.x;
    if (b < NPART) scatter_body(b, (int*)smem, src, dstp, gcnt, part, E, chunk);
    else           gemm_body(b - NPART, smem, Xv, W1s, Y, N);
}

// ======== FUSED layer-1 gather + relu + layer-2 GEMM (one block = 16 nodes) ========
// Gather phase: 16 threads/node, uint4.  H[n] = relu(dis[n]*(sum_s dis[s]*Y1[s]
// + dis[n]*Y1[n]) + b1), staged bf16 in LDS [16][136].  MFMA phase: the block's
// 16 H-rows are one M-tile; wave w computes output cols [w*32, w*32+32) via 8x
// mfma_16x16x32 with B-frags preloaded from swizzled W2s (32KB, L2-hot).
// Epilogue scales rows by dis[n] (so the layer-2 gather does plain adds) and
// stores coalesced bf16.  No early returns: invalid nodes contribute zero rows
// and hit all barriers.  [measured round 8: 75.7us; known-good, unchanged]
__global__ __launch_bounds__(256) void k_gather_gemm(
    const int* __restrict__ R, const int* __restrict__ adj,
    const unsigned short* __restrict__ Y1, const float* __restrict__ dis,
    const float* __restrict__ b1, const unsigned short* __restrict__ W2s,
    unsigned short* __restrict__ Y2, int N)
{
    __shared__ __align__(16) unsigned short Hs[16][136];

    const int wave = threadIdx.x >> 6;
    const int lane = threadIdx.x & 63;
    const int q = lane >> 4, nn = lane & 15;

    // B-frags for this wave's two 16-col tiles (ct = 2*wave, 2*wave+1), kk=0..3.
    short8 bfrag[8];
#pragma unroll
    for (int kk = 0; kk < 4; ++kk)
#pragma unroll
        for (int c = 0; c < 2; ++c) {
            int ct = wave * 2 + c;
            bfrag[kk * 2 + c] =
                *(const short8*)(W2s + ((((kk * 8 + ct) * 4 + q) * 16 + nn) << 3));
        }

    // ---- gather phase ----
    const int nl = threadIdx.x >> 4;            // node-local 0..15
    const int n  = blockIdx.x * 16 + nl;
    const int j  = (threadIdx.x & 15) * 8;      // 8 dims per thread
    const bool valid = n < N;

    float a[8];
#pragma unroll
    for (int k = 0; k < 8; ++k) a[k] = 0.f;

    if (valid) {
        float dv = dis[n];
        uint4 sv = *(const uint4*)(Y1 + (size_t)n * EMB + j);
        acc_fma8(sv, dv, a);                    // self term

        int e = R[n];
        const int re = R[n + 1];
        for (; e + 3 < re; e += 4) {
            int s0 = adj[e], s1 = adj[e + 1], s2 = adj[e + 2], s3 = adj[e + 3];
            float d0 = dis[s0], d1 = dis[s1], d2 = dis[s2], d3 = dis[s3];
            uint4 v0 = *(const uint4*)(Y1 + (size_t)s0 * EMB + j);
            uint4 v1 = *(const uint4*)(Y1 + (size_t)s1 * EMB + j);
            uint4 v2 = *(const uint4*)(Y1 + (size_t)s2 * EMB + j);
            uint4 v3 = *(const uint4*)(Y1 + (size_t)s3 * EMB + j);
            acc_fma8(v0, d0, a); acc_fma8(v1, d1, a);
            acc_fma8(v2, d2, a); acc_fma8(v3, d3, a);
        }
        for (; e < re; ++e) {
            int s0 = adj[e];
            uint4 v0 = *(const uint4*)(Y1 + (size_t)s0 * EMB + j);
            acc_fma8(v0, dis[s0], a);
        }

        float4 bb0 = *(const float4*)(b1 + j);
        float4 bb1 = *(const float4*)(b1 + j + 4);
        a[0] = fmaxf(dv * a[0] + bb0.x, 0.f);
        a[1] = fmaxf(dv * a[1] + bb0.y, 0.f);
        a[2] = fmaxf(dv * a[2] + bb0.z, 0.f);
        a[3] = fmaxf(dv * a[3] + bb0.w, 0.f);
        a[4] = fmaxf(dv * a[4] + bb1.x, 0.f);
        a[5] = fmaxf(dv * a[5] + bb1.y, 0.f);
        a[6] = fmaxf(dv * a[6] + bb1.z, 0.f);
        a[7] = fmaxf(dv * a[7] + bb1.w, 0.f);
    }

    // pack H row to LDS (invalid rows = zeros)
    {
        uint4 pk;
        pk.x = (unsigned)f2bf(a[0]) | ((unsigned)f2bf(a[1]) << 16);
        pk.y = (unsigned)f2bf(a[2]) | ((unsigned)f2bf(a[3]) << 16);
        pk.z = (unsigned)f2bf(a[4]) | ((unsigned)f2bf(a[5]) << 16);
        pk.w = (unsigned)f2bf(a[6]) | ((unsigned)f2bf(a[7]) << 16);
        *(uint4*)(&Hs[nl][j]) = pk;
    }
    __syncthreads();

    // ---- MFMA phase: 16x128 H  @  128x128 W2 ----
    f32x4 acc0 = (f32x4){0.f, 0.f, 0.f, 0.f};
    f32x4 acc1 = (f32x4){0.f, 0.f, 0.f, 0.f};
#pragma unroll
    for (int kk = 0; kk < 4; ++kk) {
        short8 af = *(const short8*)(&Hs[nn][kk * 32 + q * 8]);
        acc0 = __builtin_amdgcn_mfma_f32_16x16x32_bf16(af, bfrag[kk * 2 + 0], acc0, 0, 0, 0);
        acc1 = __builtin_amdgcn_mfma_f32_16x16x32_bf16(af, bfrag[kk * 2 + 1], acc1, 0, 0, 0);
    }
    __syncthreads();   // A-frag reads done block-wide before restage

    // dis-scale rows, restage for coalesced store.  D map: row m=q*4+r, col nn.
    const int ct0 = wave * 2, ct1 = wave * 2 + 1;
#pragma unroll
    for (int r = 0; r < 4; ++r) {
        int m = q * 4 + r;
        int gm = blockIdx.x * 16 + m;
        float dm = dis[gm < N ? gm : N - 1];
        Hs[m][ct0 * 16 + nn] = f2bf(acc0[r] * dm);
        Hs[m][ct1 * 16 + nn] = f2bf(acc1[r] * dm);
    }
    __syncthreads();

    // coalesced store: 16 rows x 256B = 4KB, 16B per thread
    {
        int row = threadIdx.x >> 4, off = threadIdx.x & 15;
        int gr = blockIdx.x * 16 + row;
        if (gr < N) {
            uint4 v = *(const uint4*)(&Hs[row][off * 8]);
            *((uint4*)(Y2 + (size_t)gr * EMB) + off) = v;
        }
    }
}

// ------- layer-2 gather: out = dis[n]*(sum + self) + b2 (f32) -------
// PROVEN SHAPE (rounds 0/5/6): 32 threads/node, uint2 (8B/lane), unroll-4.
// A wave's 64 lanes cover 2 nodes reading full contiguous 256-B rows.
// Y2 rows are pre-scaled by dis[src] in k_gather_gemm -> plain adds.
__global__ __launch_bounds__(256) void k_gather_out(
    const int* __restrict__ R, const int* __restrict__ adj,
    const unsigned short* __restrict__ Y, const float* __restrict__ dis,
    const float* __restrict__ bias, float* __restrict__ out, int N)
{
    int t = blockIdx.x * 256 + threadIdx.x;
    int n = t >> 5;
    if (n >= N) return;
    int j = (t & 31) * 4;

    float a0 = 0.f, a1 = 0.f, a2 = 0.f, a3 = 0.f;
    uint2 sv = *(const uint2*)(Y + (size_t)n * EMB + j);
    acc_bf4(sv, a0, a1, a2, a3);

    int e = R[n];
    const int re = R[n + 1];
    for (; e + 3 < re; e += 4) {
        int s0 = adj[e], s1 = adj[e + 1], s2 = adj[e + 2], s3 = adj[e + 3];
        uint2 v0 = *(const uint2*)(Y + (size_t)s0 * EMB + j);
        uint2 v1 = *(const uint2*)(Y + (size_t)s1 * EMB + j);
        uint2 v2 = *(const uint2*)(Y + (size_t)s2 * EMB + j);
        uint2 v3 = *(const uint2*)(Y + (size_t)s3 * EMB + j);
        acc_bf4(v0, a0, a1, a2, a3); acc_bf4(v1, a0, a1, a2, a3);
        acc_bf4(v2, a0, a1, a2, a3); acc_bf4(v3, a0, a1, a2, a3);
    }
    for (; e < re; ++e) {
        uint2 v0 = *(const uint2*)(Y + (size_t)adj[e] * EMB + j);
        acc_bf4(v0, a0, a1, a2, a3);
    }

    const float dv = dis[n];
    float4 b = *(const float4*)(bias + j);
    float4 o = { dv * a0 + b.x, dv * a1 + b.y,
                 dv * a2 + b.z, dv * a3 + b.w };
    *(float4*)(out + (size_t)n * EMB + j) = o;
}

extern "C" void kernel_launch(void* const* d_in, const int* in_sizes, int n_in,
                              void* d_out, int out_size, void* d_ws, size_t ws_size,
                              hipStream_t stream) {
    const int* ei = (const int*)d_in[0];
    const int E = in_sizes[0] / 2;
    const float* emb = (const float*)d_in[2];
    const int N = in_sizes[2] / EMB;
    const float* W1 = (const float*)d_in[3];
    const float* b1 = (const float*)d_in[4];
    const float* W2 = (const float*)d_in[5];
    const float* b2 = (const float*)d_in[6];
    float* out = (float*)d_out;

    const int* src = ei;
    const int* dstp = ei + E;

    // ws: dis | R | base | tot | gcnt | adj | W1s | W2s | Y2b (part overlays Y2b;
    // dead before k_gather_gemm writes it).  Y1b lives in d_out bytes (dead
    // before k_gather_out writes d_out f32).
    char* w = (char*)d_ws;
    auto take = [&](size_t bytes) { char* p = w; w += (bytes + 511) & ~(size_t)511; return p; };
    float* dis  = (float*)take((size_t)N * 4);
    int*   R    = (int*)  take((size_t)(N + 1) * 4);
    int*   base = (int*)  take((size_t)(NBUC + 1) * 4);
    int*   tot  = (int*)  take((size_t)NBUC * 4);
    int*   gcnt = (int*)  take((size_t)NBUC * 4);
    int*   adj  = (int*)  take((size_t)E * 4);
    unsigned short* W1s = (unsigned short*)take((size_t)EMB * EMB * 2);
    unsigned short* W2s = (unsigned short*)take((size_t)EMB * EMB * 2);
    unsigned short* Y2b = (unsigned short*)take((size_t)N * EMB * 2);
    int*   part = (int*)Y2b;                                 // overlay (dead before Y2b)
    unsigned short* Y1b = (unsigned short*)d_out;            // overlay in d_out

    const int NB = (N + 127) / 128;
    const int chunk = (E + NPART - 1) / NPART;
    const int gM = (N + 63) / 64;            // MFMA gemm blocks (layer 1)
    const int gF = (N + 15) / 16;            // fused gather+gemm blocks (16 nodes each)
    const int gG = (N * 32 + 255) / 256;     // layer-2 gather blocks (32 thr/node)

    // --- stage 0: zero bucket totals ---
    hipMemsetAsync(tot, 0, (size_t)NBUC * 4, stream);

    // --- K1: edge histogram -> tot, in parallel with weight pre-swizzle ---
    k_start<<<NPART + PREPB, 256, 0, stream>>>(dstp, tot, E, chunk, W1, W2, W1s, W2s);

    // --- K2: scan totals -> base, init cursors gcnt ---
    p_scan<<<1, NBUC, 0, stream>>>(tot, base, gcnt, E);

    // --- K3: reservation scatter in parallel with layer-1 GEMM (unscaled Y1b) ---
    k_mid<<<NPART + gM, 256, 0, stream>>>(src, dstp, gcnt, part, E, chunk,
                                          emb, W1s, Y1b, N);

    // --- K4: bucket -> CSR (R, adj, dis) ---
    p3_csr<<<NB, 256, 0, stream>>>(part, base, R, adj, dis, N, E);

    // --- K5: FUSED gather1 + relu + gemm2 -> Y2b = dis * (H @ W2), bf16 ---
    k_gather_gemm<<<gF, 256, 0, stream>>>(R, adj, Y1b, dis, b1, W2s, Y2b, N);

    // --- K6: layer-2 gather -> out = dis*(sum + self) + b2, f32 ---
    k_gather_out<<<gG, 256, 0, stream>>>(R, adj, Y2b, dis, b2, out, N);
}